// Round 12
// baseline (395.068 us; speedup 1.0000x reference)
//
#include <hip/hip_runtime.h>
#include <hip/hip_cooperative_groups.h>
#include <cstdint>

namespace cg = cooperative_groups;

#define N_ANCH 8400
#define CBLK 132              // ceil(8400/64)
#define SCORE_THR 0.5f
#define NBLOCKS 256
#define NTHREADS 512

typedef unsigned long long u64;
typedef unsigned int u32;

// Sort key: ascending sort == (valid score descending, then index ascending,
// invalid last by index ascending) — exactly matches
// argsort(-where(valid, s, -inf)) with stable ties.
__device__ __forceinline__ u64 sort_key(float s, int idx) {
  u32 k32 = (s >= SCORE_THR) ? ~__float_as_uint(s) : 0xFFFFFFFFu;
  return ((u64)k32 << 32) | (u32)idx;
}

__device__ __forceinline__ u64 readlane_u64(u64 v, int l) {
  u32 rlo = (u32)__builtin_amdgcn_readlane((int)(u32)v, l);
  u32 rhi = (u32)__builtin_amdgcn_readlane((int)(u32)(v >> 32), l);
  return ((u64)rhi << 32) | rlo;
}

// Single cooperative kernel: P1 rank -> grid.sync -> P2 mask -> grid.sync ->
// P3 nms + P4 output (block 0 only; other blocks exit). Eliminates the
// 3-dispatch launch/gap overhead (~90 us constant residual across R2-R11).
// Phase bodies are VERBATIM ports of the R8-proven kernels.
__global__ void __launch_bounds__(NTHREADS, 2)
fused_kernel(const float* __restrict__ raw,
             float4* __restrict__ sbox,
             float* __restrict__ sscore,
             u64* __restrict__ mask,
             float* __restrict__ out) {
  #pragma clang fp contract(off)
  cg::grid_group grid = cg::this_grid();

  __shared__ u64 keepw[CBLK];
  __shared__ u64 rem4[4][CBLK];
  __shared__ float4 cbox[64];
  __shared__ float carea[64];

  int tid = threadIdx.x;
  int wave = tid >> 6, lane = tid & 63;

  // ================= P1: rank + scatter (R8 rank_kernel, wave-stride) =====
  {
    int gw = blockIdx.x * 8 + wave;              // 2048 waves total
    for (int row = gw; row < N_ANCH; row += NBLOCKS * 8) {
      float si = raw[4 * N_ANCH + row];
      u64 ki = sort_key(si, row);
      int cnt = 0;
      for (int j = lane; j < N_ANCH; j += 64) {
        float sj = raw[4 * N_ANCH + j];
        cnt += (sort_key(sj, j) < ki) ? 1 : 0;
      }
      #pragma unroll
      for (int d = 1; d < 64; d <<= 1) cnt += __shfl_xor(cnt, d, 64);
      if (lane == 0) {
        float cx = raw[row], cy = raw[N_ANCH + row];
        float w = raw[2 * N_ANCH + row], h = raw[3 * N_ANCH + row];
        float hw = w * 0.5f, hh = h * 0.5f;
        sbox[cnt] = make_float4(cx - hw, cy - hh, cx + hw, cy + hh);
        sscore[cnt] = si;
      }
    }
  }
  __threadfence();
  grid.sync();
  __threadfence();

  // ================= P2: suppression bitmask (R8 math, 512-row tiles) =====
  // Tiles: 132 col-blocks x 17 row-groups(512) = 2244; grid-stride 256
  // blocks x 9 uniform iterations; skips evaluated uniformly per tile,
  // barriers OUTSIDE all guards.
  {
    for (int k = 0; k < 9; ++k) {
      int idx = blockIdx.x + k * NBLOCKS;
      bool tval = (idx < 2244);
      int cb = 0, i0 = 0;
      bool skip = true;
      if (tval) {
        cb = idx % 132;
        i0 = (idx / 132) * 512;                  // <= 8192 < 8400
        skip = (cb * 64 + 63 < i0) ||            // whole tile lower-tri
               !(sscore[i0] >= SCORE_THR) ||     // all rows invalid
               !(sscore[cb * 64] >= SCORE_THR);  // all cols invalid
      }
      __syncthreads();                           // WAR: cbox from prev iter
      if (!skip && tid < 64) {
        int j = cb * 64 + tid;
        float4 bj = (j < N_ANCH) ? sbox[j] : make_float4(0.f, 0.f, 0.f, 0.f);
        cbox[tid] = bj;
        carea[tid] = (bj.z - bj.x) * (bj.w - bj.y);
      }
      __syncthreads();
      if (!skip) {
        int i = i0 + tid;
        if (i < N_ANCH && i < (cb + 1) * 64) {   // rows below diag: never read
          float4 bi = sbox[i];
          float ai = (bi.z - bi.x) * (bi.w - bi.y);
          int j0 = cb * 64;
          u64 word = 0;
          for (int jj = 0; jj < 64; ++jj) {
            int jg = j0 + jj;
            if (jg <= i || jg >= N_ANCH) continue;
            float4 bb = cbox[jj];
            float ltx = fmaxf(bi.x, bb.x), lty = fmaxf(bi.y, bb.y);
            float rbx = fminf(bi.z, bb.z), rby = fminf(bi.w, bb.w);
            float wx = fmaxf(rbx - ltx, 0.f), wy = fmaxf(rby - lty, 0.f);
            float inter = wx * wy;
            float uni = (ai + carea[jj]) - inter;  // ref op order
            float iou = inter / fmaxf(uni, 1e-9f); // IEEE div
            if (iou > 0.5f) word |= (1ull << jj);
          }
          mask[(u64)i * CBLK + cb] = word;
        }
      }
    }
  }
  __threadfence();
  grid.sync();
  __threadfence();

  if (blockIdx.x != 0) return;                   // no further grid syncs

  // ================= P3: serial NMS (R8 nms_kernel, VERBATIM) =============
  int s = wave >> 2, q = wave & 3;

  float s0 = sscore[lane * 132];                 // 63*132 = 8316 < 8400
  u64 b0 = __ballot(s0 >= SCORE_THR);
  int cnt1 = (int)__popcll(b0);
  int n_valid = 0;
  if (cnt1 > 0) {
    int a = (cnt1 - 1) * 132 + 1;                // rows < a known valid
    int i1 = a + 3 * lane;
    float t1 = (i1 + 0 < N_ANCH) ? sscore[i1 + 0] : -1.f;
    float t2 = (i1 + 1 < N_ANCH) ? sscore[i1 + 1] : -1.f;
    float t3 = (i1 + 2 < N_ANCH) ? sscore[i1 + 2] : -1.f;
    u64 q1 = __ballot(t1 >= SCORE_THR);
    u64 q2 = __ballot(t2 >= SCORE_THR);
    u64 q3 = __ballot(t3 >= SCORE_THR);
    n_valid = a + (int)__popcll(q1) + (int)__popcll(q2) + (int)__popcll(q3);
  }
  int VB = (n_valid + 63) >> 6;                  // number of valid 64-blocks

  for (int b = tid; b < CBLK; b += 512) keepw[b] = 0;
  for (int x = tid; x < 4 * CBLK; x += 512) ((u64*)rem4)[x] = 0;
  // first loop-top barrier (lgkmcnt(0)+s_barrier) publishes the zeroing

  u64 v[16];                                     // per-wave tile (32 VGPRs)
  auto issue_tile = [&](int tt) {                // tile consumed at iter tt
    int c = tt + 1 + 64 * s + lane;
    bool ok = (c < VB);
    const u64* bp = mask + (u64)(tt * 64 + 16 * q) * CBLK + c;
    #pragma unroll
    for (int i = 0; i < 16; ++i) v[i] = ok ? bp[(u64)i * CBLK] : 0ull;
  };

  u64 mw_pref = 0;
  if (VB > 0) {
    mw_pref = mask[(u64)lane * CBLK];
    if (VB >= 2) issue_tile(0);
  }

  for (int t = 0; t < VB; ++t) {
    // LDS-only drain + barrier: global prefetches stay in flight
    asm volatile("s_waitcnt lgkmcnt(0)\ns_barrier" ::: "memory");

    u64 remb = rem4[0][t] | rem4[1][t] | rem4[2][t] | rem4[3][t];
    int remn = n_valid - t * 64;                 // >= 1
    u64 vmask = (remn >= 64) ? ~0ull : ((1ull << remn) - 1ull);
    u64 act = vmask & ~remb;

    // ---- scan (ballot fast path; redundant & identical in all waves)
    u64 mw = mw_pref;
    u64 sup = __ballot((((act >> lane) & 1ull) != 0ull) && (mw != 0ull));
    u64 a = act, kw = 0;
    while (a) {
      u64 as = a & sup;
      if (as == 0ull) { kw |= a; break; }
      int f = (int)__builtin_ctzll(as);
      u64 below = a & ((1ull << f) - 1ull);
      kw |= below | (1ull << f);
      u64 ml = readlane_u64(mw, f);
      a &= ~(below | (1ull << f) | ml);
    }
    if (tid == 0) keepw[t] = kw;

    // scalarized keep word
    u32 kwlo = (u32)__builtin_amdgcn_readfirstlane((int)(u32)kw);
    u32 kwhi = (u32)__builtin_amdgcn_readfirstlane((int)(u32)(kw >> 32));
    u64 kws = ((u64)kwhi << 32) | kwlo;

    // ---- consume tile (issued last iteration): masked OR + plain LDS |=
    if (t < VB - 1) {
      u64 acc = 0;
      #pragma unroll
      for (int i = 0; i < 16; ++i) {
        u64 sm = (u64)0 - ((kws >> (16 * q + i)) & 1ull);
        acc |= v[i] & sm;
      }
      int c = t + 1 + 64 * s + lane;
      if (c < VB) rem4[q][c] |= acc;             // exclusive (q,c) cell
    }

    // ---- prefetch diag for t+1, issue tile for t+1 (R8 positions)
    if (t + 1 < VB) {
      int rn = (t + 1) * 64 + lane;
      rn = (rn < N_ANCH) ? rn : (N_ANCH - 1);
      mw_pref = mask[(u64)rn * CBLK + (t + 1)];
      if (t + 1 < VB - 1) issue_tile(t + 1);
    }

    // ---- rare far window [t+129, t+192) — only when VB > t+129
    if (t + 129 < VB && s == 1) {
      int c2 = t + 129 + lane;
      if (c2 < VB) {
        const u64* bp = mask + (u64)(t * 64 + 16 * q) * CBLK + c2;
        u64 acc2 = 0;
        #pragma unroll
        for (int i = 0; i < 16; ++i) {
          u64 sm = (u64)0 - ((kws >> (16 * q + i)) & 1ull);
          acc2 |= bp[(u64)i * CBLK] & sm;
        }
        rem4[q][c2] |= acc2;                     // disjoint from c (>t+128)
      }
    }
  }
  __syncthreads();

  // ================= P4: fused masked output (R8 verbatim) ================
  for (int r2 = tid; r2 < N_ANCH; r2 += 512) {
    u64 kv = keepw[r2 >> 6];
    bool kp = (kv >> (r2 & 63)) & 1ull;
    float4 b4 = sbox[r2];
    float sc = sscore[r2];
    float* o = out + r2 * 5;
    o[0] = kp ? b4.x : 0.f;
    o[1] = kp ? b4.y : 0.f;
    o[2] = kp ? b4.z : 0.f;
    o[3] = kp ? b4.w : 0.f;
    o[4] = kp ? sc : 0.f;
  }
}

extern "C" void kernel_launch(void* const* d_in, const int* in_sizes, int n_in,
                              void* d_out, int out_size, void* d_ws, size_t ws_size,
                              hipStream_t stream) {
  const float* raw = (const float*)d_in[0];
  float* out = (float*)d_out;
  char* ws = (char*)d_ws;
  // ws layout: sbox (8448*16 B) | sscore (8448*4 B) | mask (8400*132*8 B) ≈ 9.04 MB
  float4* sbox = (float4*)ws;
  float* sscore = (float*)(ws + 8448 * 16);
  u64* mask = (u64*)(ws + 8448 * 16 + 8448 * 4);

  void* args[] = {(void*)&raw, (void*)&sbox, (void*)&sscore,
                  (void*)&mask, (void*)&out};
  hipLaunchCooperativeKernel((const void*)fused_kernel, dim3(NBLOCKS),
                             dim3(NTHREADS), args, 0, stream);
}

// Round 13
// 187.080 us; speedup vs baseline: 2.1118x; 2.1118x over previous
//
#include <hip/hip_runtime.h>
#include <cstdint>

#define N_ANCH 8400
#define CBLK 132              // ceil(8400/64)
#define SCORE_THR 0.5f

typedef unsigned long long u64;
typedef unsigned int u32;

// Sort key: ascending sort == (valid score descending, then index ascending,
// invalid last by index ascending) — exactly matches
// argsort(-where(valid, s, -inf)) with stable ties.
__device__ __forceinline__ u64 sort_key(float s, int idx) {
  u32 k32 = (s >= SCORE_THR) ? ~__float_as_uint(s) : 0xFFFFFFFFu;
  return ((u64)k32 << 32) | (u32)idx;
}

__device__ __forceinline__ u64 readlane_u64(u64 v, int l) {
  u32 rlo = (u32)__builtin_amdgcn_readlane((int)(u32)v, l);
  u32 rhi = (u32)__builtin_amdgcn_readlane((int)(u32)(v >> 32), l);
  return ((u64)rhi << 32) | rlo;
}

// One 64-lane wave per anchor: rank = #{keys smaller}, then scatter
// decoded box + score into sorted position.
__global__ void __launch_bounds__(256) rank_kernel(const float* __restrict__ raw,
                                                   float4* __restrict__ sbox,
                                                   float* __restrict__ sscore) {
  #pragma clang fp contract(off)
  int tid = blockIdx.x * 256 + threadIdx.x;
  int row = tid >> 6, lane = tid & 63;
  if (row >= N_ANCH) return;
  float si = raw[4 * N_ANCH + row];
  u64 ki = sort_key(si, row);
  int cnt = 0;
  for (int j = lane; j < N_ANCH; j += 64) {
    float sj = raw[4 * N_ANCH + j];
    cnt += (sort_key(sj, j) < ki) ? 1 : 0;
  }
  #pragma unroll
  for (int d = 1; d < 64; d <<= 1) cnt += __shfl_xor(cnt, d, 64);
  if (lane == 0) {
    float cx = raw[row], cy = raw[N_ANCH + row];
    float w = raw[2 * N_ANCH + row], h = raw[3 * N_ANCH + row];
    float hw = w * 0.5f, hh = h * 0.5f;
    sbox[cnt] = make_float4(cx - hw, cy - hh, cx + hw, cy + hh);
    sscore[cnt] = si;
  }
}

// Suppression bitmask over sorted boxes (R8-proven version + nontemporal
// stores). 256 threads = 256 rows x 64 cols per block; grid (CBLK, 33).
// mask[i*CBLK+cb] bit jj set iff j=cb*64+jj has j>i, j<N, iou(i,j) > 0.5.
// Skips tiles below the diagonal and tiles with all-invalid rows/cols
// (validity is a prefix in sorted order). NT stores evict the lines from
// the writing XCD's L2 so nms_kernel (one CU, one XCD) reads them clean
// from L3/memory instead of the dirty-remote-L2 probe path.
__global__ void __launch_bounds__(256) mask_kernel(const float4* __restrict__ sbox,
                                                   const float* __restrict__ sscore,
                                                   u64* __restrict__ mask) {
  #pragma clang fp contract(off)
  int cb = blockIdx.x;
  int i0 = blockIdx.y * 256;
  if (cb * 64 + 63 < i0) return;
  if (!(sscore[i0] >= SCORE_THR)) return;
  if (!(sscore[cb * 64] >= SCORE_THR)) return;
  int t = threadIdx.x;
  __shared__ float4 cbox[64];
  __shared__ float carea[64];
  int j0 = cb * 64;
  if (t < 64) {
    int j = j0 + t;
    float4 bj = (j < N_ANCH) ? sbox[j] : make_float4(0.f, 0.f, 0.f, 0.f);
    cbox[t] = bj;
    carea[t] = (bj.z - bj.x) * (bj.w - bj.y);
  }
  __syncthreads();
  int i = i0 + t;
  if (i >= N_ANCH || i >= (cb + 1) * 64) return;
  float4 bi = sbox[i];
  float ai = (bi.z - bi.x) * (bi.w - bi.y);
  u64 word = 0;
  for (int jj = 0; jj < 64; ++jj) {
    int jg = j0 + jj;
    if (jg <= i || jg >= N_ANCH) continue;
    float4 bb = cbox[jj];
    float ltx = fmaxf(bi.x, bb.x), lty = fmaxf(bi.y, bb.y);
    float rbx = fminf(bi.z, bb.z), rby = fminf(bi.w, bb.w);
    float wx = fmaxf(rbx - ltx, 0.f), wy = fmaxf(rby - lty, 0.f);
    float inter = wx * wy;
    float uni = (ai + carea[jj]) - inter;      // same op order as reference
    float iou = inter / fmaxf(uni, 1e-9f);     // IEEE div, matches numpy
    if (iou > 0.5f) word |= (1ull << jj);
  }
  __builtin_nontemporal_store(word, &mask[(u64)i * CBLK + cb]);
}

// 512 threads = 8 waves = (2 col-sets s) x (4 row-quarters q). EXACT R8
// structure (proven 80 us) — do not reorder the K-loop (R9/R10/R11 all
// regressed). Iteration t: wave (s,q) applies rows 16q..16q+15 of block t
// to columns t+1+64s+lane. Columns [t+1,t+128] covered every iter; rare far
// window [t+129,t+192] => complete for VB<=192 (max 132). removed = 4
// quarter-partial LDS arrays with EXCLUSIVE (q,c) cells => plain |= (no
// atomics: flat atomics enter the vmcnt FIFO and serialize the prefetch
// pipeline). Barrier drains LDS ONLY — global prefetches stay in flight.
__global__ void __launch_bounds__(512, 1) nms_kernel(const float4* __restrict__ sbox,
                                                     const float* __restrict__ sscore,
                                                     const u64* __restrict__ mask,
                                                     float* __restrict__ out) {
  __shared__ u64 keepw[CBLK];
  __shared__ u64 rem4[4][CBLK];
  int tid = threadIdx.x;
  int wave = tid >> 6, lane = tid & 63;
  int s = wave >> 2, q = wave & 3;

  // ---- n_valid via 2-round probe (redundant in every wave — same result)
  float s0 = sscore[lane * 132];                 // 63*132 = 8316 < 8400
  u64 b0 = __ballot(s0 >= SCORE_THR);
  int cnt1 = (int)__popcll(b0);
  int n_valid = 0;
  if (cnt1 > 0) {
    int a = (cnt1 - 1) * 132 + 1;                // rows < a known valid
    int i1 = a + 3 * lane;
    float t1 = (i1 + 0 < N_ANCH) ? sscore[i1 + 0] : -1.f;
    float t2 = (i1 + 1 < N_ANCH) ? sscore[i1 + 1] : -1.f;
    float t3 = (i1 + 2 < N_ANCH) ? sscore[i1 + 2] : -1.f;
    u64 q1 = __ballot(t1 >= SCORE_THR);
    u64 q2 = __ballot(t2 >= SCORE_THR);
    u64 q3 = __ballot(t3 >= SCORE_THR);
    n_valid = a + (int)__popcll(q1) + (int)__popcll(q2) + (int)__popcll(q3);
  }
  int VB = (n_valid + 63) >> 6;                  // number of valid 64-blocks

  for (int b = tid; b < CBLK; b += 512) keepw[b] = 0;
  for (int x = tid; x < 4 * CBLK; x += 512) ((u64*)rem4)[x] = 0;
  // first loop-top barrier (lgkmcnt(0)+s_barrier) publishes the zeroing

  u64 v[16];                                     // per-wave tile (32 VGPRs)
  auto issue_tile = [&](int tt) {                // tile consumed at iter tt
    int c = tt + 1 + 64 * s + lane;
    bool ok = (c < VB);
    const u64* bp = mask + (u64)(tt * 64 + 16 * q) * CBLK + c;
    #pragma unroll
    for (int i = 0; i < 16; ++i) v[i] = ok ? bp[(u64)i * CBLK] : 0ull;
  };

  // prologue: diag words + tile for t=0
  u64 mw_pref = 0;
  if (VB > 0) {
    mw_pref = mask[(u64)lane * CBLK];
    if (VB >= 2) issue_tile(0);
  }

  for (int t = 0; t < VB; ++t) {
    // LDS-only drain + barrier: global prefetches stay in flight
    asm volatile("s_waitcnt lgkmcnt(0)\ns_barrier" ::: "memory");

    u64 remb = rem4[0][t] | rem4[1][t] | rem4[2][t] | rem4[3][t];
    int remn = n_valid - t * 64;                 // >= 1
    u64 vmask = (remn >= 64) ? ~0ull : ((1ull << remn) - 1ull);
    u64 act = vmask & ~remb;

    // ---- scan (ballot fast path; redundant & identical in all waves)
    u64 mw = mw_pref;
    u64 sup = __ballot((((act >> lane) & 1ull) != 0ull) && (mw != 0ull));
    u64 a = act, kw = 0;
    while (a) {
      u64 as = a & sup;
      if (as == 0ull) { kw |= a; break; }
      int f = (int)__builtin_ctzll(as);
      u64 below = a & ((1ull << f) - 1ull);
      kw |= below | (1ull << f);
      u64 ml = readlane_u64(mw, f);
      a &= ~(below | (1ull << f) | ml);
    }
    if (tid == 0) keepw[t] = kw;

    // scalarized keep word
    u32 kwlo = (u32)__builtin_amdgcn_readfirstlane((int)(u32)kw);
    u32 kwhi = (u32)__builtin_amdgcn_readfirstlane((int)(u32)(kw >> 32));
    u64 kws = ((u64)kwhi << 32) | kwlo;

    // ---- consume tile (issued last iteration): masked OR + plain LDS |=
    if (t < VB - 1) {
      u64 acc = 0;
      #pragma unroll
      for (int i = 0; i < 16; ++i) {
        u64 sm = (u64)0 - ((kws >> (16 * q + i)) & 1ull);
        acc |= v[i] & sm;
      }
      int c = t + 1 + 64 * s + lane;
      if (c < VB) rem4[q][c] |= acc;             // exclusive (q,c) cell
    }

    // ---- prefetch diag for t+1, issue tile for t+1
    if (t + 1 < VB) {
      int rn = (t + 1) * 64 + lane;
      rn = (rn < N_ANCH) ? rn : (N_ANCH - 1);
      mw_pref = mask[(u64)rn * CBLK + (t + 1)];
      if (t + 1 < VB - 1) issue_tile(t + 1);
    }

    // ---- rare far window [t+129, t+192) — only when VB > t+129 (never at
    // VB~66; <=3 iterations even at worst-case VB=132)
    if (t + 129 < VB && s == 1) {
      int c2 = t + 129 + lane;
      if (c2 < VB) {
        const u64* bp = mask + (u64)(t * 64 + 16 * q) * CBLK + c2;
        u64 acc2 = 0;
        #pragma unroll
        for (int i = 0; i < 16; ++i) {
          u64 sm = (u64)0 - ((kws >> (16 * q + i)) & 1ull);
          acc2 |= bp[(u64)i * CBLK] & sm;
        }
        rem4[q][c2] |= acc2;                     // disjoint from c (>t+128)
      }
    }
  }
  __syncthreads();

  // ---- fused masked output (512 threads)
  for (int r2 = tid; r2 < N_ANCH; r2 += 512) {
    u64 kv = keepw[r2 >> 6];
    bool kp = (kv >> (r2 & 63)) & 1ull;
    float4 b4 = sbox[r2];
    float sc = sscore[r2];
    float* o = out + r2 * 5;
    o[0] = kp ? b4.x : 0.f;
    o[1] = kp ? b4.y : 0.f;
    o[2] = kp ? b4.z : 0.f;
    o[3] = kp ? b4.w : 0.f;
    o[4] = kp ? sc : 0.f;
  }
}

extern "C" void kernel_launch(void* const* d_in, const int* in_sizes, int n_in,
                              void* d_out, int out_size, void* d_ws, size_t ws_size,
                              hipStream_t stream) {
  const float* raw = (const float*)d_in[0];
  float* out = (float*)d_out;
  char* ws = (char*)d_ws;
  // ws layout: sbox (8448*16 B) | sscore (8448*4 B) | mask (8400*132*8 B) ≈ 9.04 MB
  float4* sbox = (float4*)ws;
  float* sscore = (float*)(ws + 8448 * 16);
  u64* mask = (u64*)(ws + 8448 * 16 + 8448 * 4);

  rank_kernel<<<2100, 256, 0, stream>>>(raw, sbox, sscore);
  mask_kernel<<<dim3(CBLK, 33), 256, 0, stream>>>(sbox, sscore, mask);
  nms_kernel<<<1, 512, 0, stream>>>(sbox, sscore, mask, out);
}